// Round 1
// baseline (36.926 us; speedup 1.0000x reference)
//
#include <hip/hip_runtime.h>

// HeadDetectorLoss: scalar loss over N=4194304 rows.
//   prediction (N,6) f32: [:,0:2]=class logits, [:,2:6]=box pred
//   target_class (N,) i32 in {0,1}; target_box (N,4) f32
//   out = mean(nll) + 10 * sum(mse*mask) / (1e-6 + sum(mask))
// Memory-bound streaming reduction: 184.5 MB read, 4 B written.

#define GRID 2048
#define BLOCK 256

__global__ __launch_bounds__(BLOCK) void hdl_reduce(
    const float* __restrict__ pred,
    const int*   __restrict__ tcls,
    const float* __restrict__ tbox,
    float* __restrict__ part,   // [3*GRID] partials: nll / box / cnt
    int nrows)
{
  const int tid    = blockIdx.x * BLOCK + threadIdx.x;
  const int stride = GRID * BLOCK;
  const int npairs = nrows >> 1;           // process 2 rows/thread-iter for float4 alignment

  float nll = 0.f, box = 0.f, cnt = 0.f;

  for (long long t = tid; t < npairs; t += stride) {
    // pair t = rows 2t, 2t+1: pred floats [12t, 12t+12), 48-byte aligned
    const float4 q0 = *reinterpret_cast<const float4*>(pred + 12ll * t);      // r0: l0 l1 b0 b1
    const float4 q1 = *reinterpret_cast<const float4*>(pred + 12ll * t + 4);  // r0: b2 b3 | r1: l0 l1
    const float4 q2 = *reinterpret_cast<const float4*>(pred + 12ll * t + 8);  // r1: b0 b1 b2 b3
    const float4 b0 = *reinterpret_cast<const float4*>(tbox + 8ll * t);
    const float4 b1 = *reinterpret_cast<const float4*>(tbox + 8ll * t + 4);
    const int2   c  = *reinterpret_cast<const int2*>(tcls + 2ll * t);

    { // row 0
      float m   = fmaxf(q0.x, q0.y);
      float lse = m + __logf(__expf(q0.x - m) + __expf(q0.y - m));
      nll += lse - (c.x == 0 ? q0.x : q0.y);
      float d0 = q0.z - b0.x, d1 = q0.w - b0.y, d2 = q1.x - b0.z, d3 = q1.y - b0.w;
      float mse = 0.25f * (d0*d0 + d1*d1 + d2*d2 + d3*d3);
      if (c.x != 0) { box += mse; cnt += 1.f; }
    }
    { // row 1
      float m   = fmaxf(q1.z, q1.w);
      float lse = m + __logf(__expf(q1.z - m) + __expf(q1.w - m));
      nll += lse - (c.y == 0 ? q1.z : q1.w);
      float d0 = q2.x - b1.x, d1 = q2.y - b1.y, d2 = q2.z - b1.z, d3 = q2.w - b1.w;
      float mse = 0.25f * (d0*d0 + d1*d1 + d2*d2 + d3*d3);
      if (c.y != 0) { box += mse; cnt += 1.f; }
    }
  }

  // wave64 tree reduction
  #pragma unroll
  for (int off = 32; off > 0; off >>= 1) {
    nll += __shfl_down(nll, off);
    box += __shfl_down(box, off);
    cnt += __shfl_down(cnt, off);
  }

  __shared__ float s[3][BLOCK / 64];
  const int lane = threadIdx.x & 63, w = threadIdx.x >> 6;
  if (lane == 0) { s[0][w] = nll; s[1][w] = box; s[2][w] = cnt; }
  __syncthreads();
  if (threadIdx.x == 0) {
    float a = 0.f, b = 0.f, cn = 0.f;
    #pragma unroll
    for (int i = 0; i < BLOCK / 64; ++i) { a += s[0][i]; b += s[1][i]; cn += s[2][i]; }
    part[blockIdx.x]            = a;
    part[GRID + blockIdx.x]     = b;
    part[2 * GRID + blockIdx.x] = cn;
  }
}

__global__ __launch_bounds__(BLOCK) void hdl_final(
    const float* __restrict__ part, float* __restrict__ out, int nrows)
{
  float a = 0.f, b = 0.f, c = 0.f;
  for (int i = threadIdx.x; i < GRID; i += BLOCK) {
    a += part[i];
    b += part[GRID + i];
    c += part[2 * GRID + i];
  }
  #pragma unroll
  for (int off = 32; off > 0; off >>= 1) {
    a += __shfl_down(a, off);
    b += __shfl_down(b, off);
    c += __shfl_down(c, off);
  }
  __shared__ float s[3][BLOCK / 64];
  const int lane = threadIdx.x & 63, w = threadIdx.x >> 6;
  if (lane == 0) { s[0][w] = a; s[1][w] = b; s[2][w] = c; }
  __syncthreads();
  if (threadIdx.x == 0) {
    float A = 0.f, B = 0.f, C = 0.f;
    #pragma unroll
    for (int i = 0; i < BLOCK / 64; ++i) { A += s[0][i]; B += s[1][i]; C += s[2][i]; }
    out[0] = A / (float)nrows + 10.0f * B / (1e-6f + C);
  }
}

extern "C" void kernel_launch(void* const* d_in, const int* in_sizes, int n_in,
                              void* d_out, int out_size, void* d_ws, size_t ws_size,
                              hipStream_t stream) {
  const float* pred = (const float*)d_in[0];
  const int*   tcls = (const int*)d_in[1];
  const float* tbox = (const float*)d_in[2];
  float* out  = (float*)d_out;
  float* part = (float*)d_ws;           // 3*GRID floats = 24 KB
  const int nrows = in_sizes[1];        // N from target_class

  hdl_reduce<<<GRID, BLOCK, 0, stream>>>(pred, tcls, tbox, part, nrows);
  hdl_final<<<1, BLOCK, 0, stream>>>(part, out, nrows);
}